// Round 11
// baseline (81.855 us; speedup 1.0000x reference)
//
#include <hip/hip_runtime.h>
#include <stdint.h>

typedef float  f32x4  __attribute__((ext_vector_type(4)));
typedef short  bf16x8 __attribute__((ext_vector_type(8)));
typedef int    i32x4  __attribute__((ext_vector_type(4)));
typedef unsigned int u32x2 __attribute__((ext_vector_type(2)));

#define C1f 0.70710678118654752f
#define C2f 0.5f
#define C3f 0.35355339059327373f

#define NT 1024         // 16 waves
#define CH 16           // chunk rows
#define RB 1040         // LDS row stride bytes (512*2 + 16 pad)
#define CHSZ (CH*RB)    // 16640 B
#define RPB 256         // rows per block
#define NCHUNK (RPB/CH) // 16

__device__ __forceinline__ unsigned int f2b(float f) {
    unsigned int u; __builtin_memcpy(&u, &f, 4);
    u += 0x7fffu + ((u >> 16) & 1u);          // RTNE f32 -> bf16
    return u >> 16;
}
__device__ __forceinline__ unsigned int pack2(float lo, float hi) {
    return f2b(lo) | (f2b(hi) << 16);
}
__device__ __forceinline__ bf16x8 cast8(i32x4 v) {
    bf16x8 r; __builtin_memcpy(&r, &v, 16); return r;
}

// LDS-only barrier: orders ds ops across the workgroup WITHOUT draining vmcnt
// (global loads/stores keep flowing across it — required for the pipeline).
__device__ __forceinline__ void lds_barrier() {
    asm volatile("s_waitcnt lgkmcnt(0)" ::: "memory");
    __builtin_amdgcn_s_barrier();
    __builtin_amdgcn_sched_barrier(0);
}
// counted vmem waits (T4): wait until <= N vmem ops outstanding
__device__ __forceinline__ void vwait1() { asm volatile("s_waitcnt vmcnt(1)" ::: "memory"); __builtin_amdgcn_sched_barrier(0); }
__device__ __forceinline__ void vwait2() { asm volatile("s_waitcnt vmcnt(2)" ::: "memory"); __builtin_amdgcn_sched_barrier(0); }
__device__ __forceinline__ void vwait3() { asm volatile("s_waitcnt vmcnt(3)" ::: "memory"); __builtin_amdgcn_sched_barrier(0); }

// G[o][i0..i0+7] as bf16x8.  G = composed DWT -> blockdiag(W) -> IDWT matrix:
// G[o][i] = 1/8*Wa[o/8][i/8] + 1/8*s2(o)s2(i)*W2[o/8][i/8]
//         + 1/4*s1(o)s1(i)*W1[o/4][i/4] + 1/2*s0(o)s0(i)*W0[o/2][i/2]
__device__ __forceinline__ bf16x8 g_frag(int o, int i0,
        const float* __restrict__ W0, const float* __restrict__ W1,
        const float* __restrict__ W2, const float* __restrict__ Wa)
{
    const float s0o = (o & 1) ? -1.f : 1.f;
    const float s1o = ((o >> 1) & 1) ? -1.f : 1.f;
    const float s2o = ((o >> 2) & 1) ? -1.f : 1.f;
    const float4 w0 = *(const float4*)(W0 + (o >> 1) * 256 + (i0 >> 1));
    const float2 w1 = *(const float2*)(W1 + (o >> 2) * 128 + (i0 >> 2));
    const float  w2 = W2[(o >> 3) * 64 + (i0 >> 3)];
    const float  wa = Wa[(o >> 3) * 64 + (i0 >> 3)];
    const float base = 0.125f * wa;
    const float c2   = 0.125f * s2o * w2;
    const float c1   = 0.25f  * s1o;
    const float c0   = 0.5f   * s0o;
    const float w0a[4] = { w0.x, w0.y, w0.z, w0.w };
    const float w1a[2] = { w1.x, w1.y };
    float g[8];
    #pragma unroll
    for (int e = 0; e < 8; ++e) {
        const float t2 = ((e >> 2) & 1) ? -c2 : c2;
        const float t1 = (((e >> 1) & 1) ? -c1 : c1) * w1a[e >> 2];
        const float t0 = ((e & 1) ? -c0 : c0) * w0a[e >> 1];
        g[e] = base + t2 + t1 + t0;
    }
    i32x4 p = { (int)pack2(g[0],g[1]), (int)pack2(g[2],g[3]),
                (int)pack2(g[4],g[5]), (int)pack2(g[6],g[7]) };
    return cast8(p);
}

// prep: build G in MFMA-fragment blob order + bias vector g.
__global__ void prep(const float* __restrict__ W0, const float* __restrict__ b0,
                     const float* __restrict__ W1, const float* __restrict__ b1,
                     const float* __restrict__ W2, const float* __restrict__ b2,
                     const float* __restrict__ Wa, const float* __restrict__ ba,
                     unsigned short* __restrict__ ws)
{
    const int gid  = blockIdx.x * 256 + threadIdx.x;   // 32768 threads
    const int blob = gid >> 6, lane = gid & 63;
    const int otg  = blob >> 4, ks = blob & 15;
    const int o  = otg * 16 + (lane & 15);
    const int i0 = ks * 32 + ((lane >> 4) * 8);
    bf16x8 f = g_frag(o, i0, W0, W1, W2, Wa);
    i32x4 p; __builtin_memcpy(&p, &f, 16);
    *(i32x4*)(ws + blob * 512 + lane * 8) = p;
    if (gid < 512) {
        float* gv = (float*)(ws + 262144);
        const int oo = gid;
        const float s0 = (oo & 1) ? -C1f : C1f;
        const float s1 = ((oo >> 1) & 1) ? -C2f : C2f;
        const float s2 = ((oo >> 2) & 1) ? -C3f : C3f;
        gv[oo] = C3f * ba[oo >> 3] + s2 * b2[oo >> 3] + s1 * b1[oo >> 2] + s0 * b0[oo >> 1];
    }
}

// main: out = x @ G^T + g.  Block: 256 rows x 256 cols (col-half), 16 waves.
// Wave owns ONE 16-col tile; full-K G (16 frags, 64 regs) loaded ONCE.
// x streams via QUAD-buffered LDS in 16-row chunks with a 2-deep counted-vmcnt
// register prefetch pipeline; barriers are lgkm-only so HBM never drains.
template<int USE_WS>
__global__ __launch_bounds__(NT, 4)
void wavelet_gemm(const float* __restrict__ x,
                  const float* __restrict__ W0, const float* __restrict__ b0,
                  const float* __restrict__ W1, const float* __restrict__ b1,
                  const float* __restrict__ W2, const float* __restrict__ b2,
                  const float* __restrict__ Wa, const float* __restrict__ ba,
                  const unsigned short* __restrict__ wsb,
                  float* __restrict__ out)
{
    __shared__ char lds[4 * CHSZ];        // 66560 B

    const int tid  = threadIdx.x;
    const int lane = tid & 63;
    const int wave = tid >> 6;            // 0..15
    const int bid  = blockIdx.x;
    const int chalf = bid & 1;
    const long rowblk = (long)(bid >> 1) * RPB;
    const int otg  = chalf * 16 + wave;   // global col-tile 0..31
    const int col0 = otg * 16;
    const int bc0  = col0 + ((lane >> 4) << 2);   // this lane's 4 out cols

    // ---- B: this wave's full-K G fragments, loaded once (64 regs) ----
    bf16x8 B[16];
    if (USE_WS) {
        #pragma unroll
        for (int ks = 0; ks < 16; ++ks)
            B[ks] = cast8(*(const i32x4*)(wsb + ((size_t)(otg * 16 + ks) * 512) + lane * 8));
    } else {
        #pragma unroll
        for (int ks = 0; ks < 16; ++ks)
            B[ks] = g_frag(col0 + (lane & 15), ks * 32 + ((lane >> 4) * 8), W0, W1, W2, Wa);
    }
    #pragma unroll
    for (int ks = 0; ks < 16; ++ks) {     // pin: no re-issue inside the loop
        i32x4 t; __builtin_memcpy(&t, &B[ks], 16);
        asm volatile("" : "+v"(t));
        __builtin_memcpy(&B[ks], &t, 16);
    }

    // bias for this lane's 4 cols
    f32x4 gv4;
    if (USE_WS) {
        const float4 g4 = *(const float4*)((const float*)(wsb + 262144) + bc0);
        gv4 = f32x4{ g4.x, g4.y, g4.z, g4.w };
    } else {
        #pragma unroll
        for (int j = 0; j < 4; ++j) {
            const int col = bc0 + j;
            const float s0 = (col & 1) ? -C1f : C1f;
            const float s1 = ((col >> 1) & 1) ? -C2f : C2f;
            const float s2 = ((col >> 2) & 1) ? -C3f : C3f;
            gv4[j] = C3f * ba[col >> 3] + s2 * b2[col >> 3] + s1 * b1[col >> 2] + s0 * b0[col >> 1];
        }
    }

    // chunk = 16 rows x 512 f32 = 2048 float4; 2 per thread
    auto ldx = [&](int c, f32x4* v) {
        const f32x4* xb = (const f32x4*)(x + (rowblk + (long)c * CH) * 512);
        v[0] = xb[tid];
        v[1] = xb[NT + tid];
    };
    auto stx = [&](int c, const f32x4* v) {
        char* base = lds + (c & 3) * CHSZ;
        #pragma unroll
        for (int i = 0; i < 2; ++i) {
            const int f = i * NT + tid;
            const int row = f >> 7, c4 = f & 127;
            u32x2 p = { pack2(v[i][0], v[i][1]), pack2(v[i][2], v[i][3]) };
            *(u32x2*)(base + row * RB + c4 * 8) = p;
        }
    };
    // compute one 16-row chunk: 16 ks, 1 m-subtile; ends with 1 f32x4 out-store
    auto compute = [&](int c) {
        const char* pa = lds + (c & 3) * CHSZ + (lane & 15) * RB + ((lane >> 4) * 16);
        f32x4 acc = {};
        #pragma unroll
        for (int ks = 0; ks < 16; ++ks) {
            bf16x8 a = cast8(*(const i32x4*)(pa + ks * 64));
            acc = __builtin_amdgcn_mfma_f32_16x16x32_bf16(B[ks], a, acc, 0, 0, 0);
        }
        const long r0 = rowblk + (long)c * CH + (lane & 15);
        *(f32x4*)(out + r0 * 512 + bc0) = acc + gv4;
    };

    // ---- prologue: fill chunk 0 (staged) and chunk 1 (in regs) ----
    f32x4 vA[2], vB2[2];
    ldx(0, vA);
    ldx(1, vB2);
    vwait2();                 // ld(0) done; ld(1) still in flight
    stx(0, vA);
    lds_barrier();

    // ---- main loop, manually unrolled x2 (static reg buffers, rule #20) ----
    #pragma unroll 1
    for (int cc = 0; cc < NCHUNK; cc += 2) {
        // c = cc (even): stage cc+1 from vB2, prefetch cc+2 into vA
        compute(cc);
        if (cc + 2 < NCHUNK) { ldx(cc + 2, vA); vwait3(); }
        else                 { vwait1(); }
        stx(cc + 1, vB2);
        lds_barrier();
        // c = cc+1 (odd): stage cc+2 from vA, prefetch cc+3 into vB2
        compute(cc + 1);
        if (cc + 2 < NCHUNK) {
            if (cc + 3 < NCHUNK) { ldx(cc + 3, vB2); vwait3(); }
            else                 { vwait1(); }
            stx(cc + 2, vA);
        }
        lds_barrier();
    }
}

extern "C" void kernel_launch(void* const* d_in, const int* in_sizes, int n_in,
                              void* d_out, int out_size, void* d_ws, size_t ws_size,
                              hipStream_t stream)
{
    const float* x  = (const float*)d_in[0];
    const float* W0 = (const float*)d_in[1];
    const float* b0 = (const float*)d_in[2];
    const float* W1 = (const float*)d_in[3];
    const float* b1 = (const float*)d_in[4];
    const float* W2 = (const float*)d_in[5];
    const float* b2 = (const float*)d_in[6];
    const float* Wa = (const float*)d_in[7];
    const float* ba = (const float*)d_in[8];
    float* out = (float*)d_out;

    const int nrows = in_sizes[0] / 512;      // 65536
    const int nblk  = (nrows / RPB) * 2;      // 512 (row-groups x col-halves)

    if (ws_size >= (size_t)(524288 + 2048)) {
        unsigned short* ws = (unsigned short*)d_ws;
        prep<<<128, 256, 0, stream>>>(W0, b0, W1, b1, W2, b2, Wa, ba, ws);
        wavelet_gemm<1><<<nblk, NT, 0, stream>>>(x, W0, b0, W1, b1, W2, b2, Wa, ba, ws, out);
    } else {
        wavelet_gemm<0><<<nblk, NT, 0, stream>>>(x, W0, b0, W1, b1, W2, b2, Wa, ba, nullptr, out);
    }
}

// Round 12
// 77.895 us; speedup vs baseline: 1.0508x; 1.0508x over previous
//
#include <hip/hip_runtime.h>
#include <stdint.h>

typedef float  f32x4  __attribute__((ext_vector_type(4)));
typedef short  bf16x8 __attribute__((ext_vector_type(8)));
typedef int    i32x4  __attribute__((ext_vector_type(4)));
typedef unsigned int u32x2 __attribute__((ext_vector_type(2)));

#define C1f 0.70710678118654752f
#define C2f 0.5f
#define C3f 0.35355339059327373f

#define NT 512          // 8 waves
#define CH 16           // chunk rows
#define RB 1040         // LDS row stride bytes (512*2 + 16 pad)
#define CHSZ (CH*RB)    // 16640 B
#define RPB 256         // rows per block
#define NCHUNK (RPB/CH) // 16
#define NCOLG 4         // col groups (128 cols each)

__device__ __forceinline__ unsigned int f2b(float f) {
    unsigned int u; __builtin_memcpy(&u, &f, 4);
    u += 0x7fffu + ((u >> 16) & 1u);          // RTNE f32 -> bf16
    return u >> 16;
}
__device__ __forceinline__ unsigned int pack2(float lo, float hi) {
    return f2b(lo) | (f2b(hi) << 16);
}
__device__ __forceinline__ bf16x8 cast8(i32x4 v) {
    bf16x8 r; __builtin_memcpy(&r, &v, 16); return r;
}

// LDS-only barrier: orders ds ops across the workgroup WITHOUT draining vmcnt.
__device__ __forceinline__ void lds_barrier() {
    asm volatile("s_waitcnt lgkmcnt(0)" ::: "memory");
    __builtin_amdgcn_s_barrier();
    __builtin_amdgcn_sched_barrier(0);
}
// wait until <=1 vmem op outstanding (the newest = our out-store may remain)
__device__ __forceinline__ void vwait1() {
    asm volatile("s_waitcnt vmcnt(1)" ::: "memory");
    __builtin_amdgcn_sched_barrier(0);
}

// G[o][i0..i0+7] as bf16x8.  G = composed DWT -> blockdiag(W) -> IDWT matrix:
// G[o][i] = 1/8*Wa[o/8][i/8] + 1/8*s2(o)s2(i)*W2[o/8][i/8]
//         + 1/4*s1(o)s1(i)*W1[o/4][i/4] + 1/2*s0(o)s0(i)*W0[o/2][i/2]
__device__ __forceinline__ bf16x8 g_frag(int o, int i0,
        const float* __restrict__ W0, const float* __restrict__ W1,
        const float* __restrict__ W2, const float* __restrict__ Wa)
{
    const float s0o = (o & 1) ? -1.f : 1.f;
    const float s1o = ((o >> 1) & 1) ? -1.f : 1.f;
    const float s2o = ((o >> 2) & 1) ? -1.f : 1.f;
    const float4 w0 = *(const float4*)(W0 + (o >> 1) * 256 + (i0 >> 1));
    const float2 w1 = *(const float2*)(W1 + (o >> 2) * 128 + (i0 >> 2));
    const float  w2 = W2[(o >> 3) * 64 + (i0 >> 3)];
    const float  wa = Wa[(o >> 3) * 64 + (i0 >> 3)];
    const float base = 0.125f * wa;
    const float c2   = 0.125f * s2o * w2;
    const float c1   = 0.25f  * s1o;
    const float c0   = 0.5f   * s0o;
    const float w0a[4] = { w0.x, w0.y, w0.z, w0.w };
    const float w1a[2] = { w1.x, w1.y };
    float g[8];
    #pragma unroll
    for (int e = 0; e < 8; ++e) {
        const float t2 = ((e >> 2) & 1) ? -c2 : c2;
        const float t1 = (((e >> 1) & 1) ? -c1 : c1) * w1a[e >> 2];
        const float t0 = ((e & 1) ? -c0 : c0) * w0a[e >> 1];
        g[e] = base + t2 + t1 + t0;
    }
    i32x4 p = { (int)pack2(g[0],g[1]), (int)pack2(g[2],g[3]),
                (int)pack2(g[4],g[5]), (int)pack2(g[6],g[7]) };
    return cast8(p);
}

// prep: build G in MFMA-fragment blob order + bias vector g.
__global__ void prep(const float* __restrict__ W0, const float* __restrict__ b0,
                     const float* __restrict__ W1, const float* __restrict__ b1,
                     const float* __restrict__ W2, const float* __restrict__ b2,
                     const float* __restrict__ Wa, const float* __restrict__ ba,
                     unsigned short* __restrict__ ws)
{
    const int gid  = blockIdx.x * 256 + threadIdx.x;   // 32768 threads
    const int blob = gid >> 6, lane = gid & 63;
    const int otg  = blob >> 4, ks = blob & 15;
    const int o  = otg * 16 + (lane & 15);
    const int i0 = ks * 32 + ((lane >> 4) * 8);
    bf16x8 f = g_frag(o, i0, W0, W1, W2, Wa);
    i32x4 p; __builtin_memcpy(&p, &f, 16);
    *(i32x4*)(ws + blob * 512 + lane * 8) = p;
    if (gid < 512) {
        float* gv = (float*)(ws + 262144);
        const int oo = gid;
        const float s0 = (oo & 1) ? -C1f : C1f;
        const float s1 = ((oo >> 1) & 1) ? -C2f : C2f;
        const float s2 = ((oo >> 2) & 1) ? -C3f : C3f;
        gv[oo] = C3f * ba[oo >> 3] + s2 * b2[oo >> 3] + s1 * b1[oo >> 2] + s0 * b0[oo >> 1];
    }
}

// main: out = x @ G^T + g.  Block: 256 rows x 128 cols, 8 waves; wave owns ONE
// 16-col tile with full-K G in regs (loaded once).  x streams via double-buffered
// 16-row LDS chunks.  33KB LDS + <=124 regs/wave => TWO blocks resident per CU,
// so one block's barrier stalls overlap the other's compute.  XCD-chunked swizzle
// co-locates the 4 col-groups of the same rows on one XCD (x shared via L2).
template<int USE_WS>
__global__ __launch_bounds__(NT, 4)
void wavelet_gemm(const float* __restrict__ x,
                  const float* __restrict__ W0, const float* __restrict__ b0,
                  const float* __restrict__ W1, const float* __restrict__ b1,
                  const float* __restrict__ W2, const float* __restrict__ b2,
                  const float* __restrict__ Wa, const float* __restrict__ ba,
                  const unsigned short* __restrict__ wsb,
                  float* __restrict__ out, int nblk)
{
    __shared__ char lds[2 * CHSZ];        // 33280 B

    const int tid  = threadIdx.x;
    const int lane = tid & 63;
    const int wave = tid >> 6;            // 0..7

    // XCD-chunked bijective swizzle (nblk % 8 == 0)
    const int cpx = nblk >> 3;
    const int lbid = ((int)blockIdx.x & 7) * cpx + ((int)blockIdx.x >> 3);
    const int colg = lbid & (NCOLG - 1);
    const long rowblk = (long)(lbid >> 2) * RPB;

    const int otg  = colg * 8 + wave;     // global col-tile 0..31
    const int col0 = otg * 16;
    const int bc0  = col0 + ((lane >> 4) << 2);   // this lane's 4 out cols

    // ---- B: this wave's full-K G fragments, loaded once (64 regs) ----
    bf16x8 B[16];
    if (USE_WS) {
        #pragma unroll
        for (int ks = 0; ks < 16; ++ks)
            B[ks] = cast8(*(const i32x4*)(wsb + ((size_t)(otg * 16 + ks) * 512) + lane * 8));
    } else {
        #pragma unroll
        for (int ks = 0; ks < 16; ++ks)
            B[ks] = g_frag(col0 + (lane & 15), ks * 32 + ((lane >> 4) * 8), W0, W1, W2, Wa);
    }
    #pragma unroll
    for (int ks = 0; ks < 16; ++ks) {     // pin: no re-issue inside the loop
        i32x4 t; __builtin_memcpy(&t, &B[ks], 16);
        asm volatile("" : "+v"(t));
        __builtin_memcpy(&B[ks], &t, 16);
    }

    // bias for this lane's 4 cols
    f32x4 gv4;
    if (USE_WS) {
        const float4 g4 = *(const float4*)((const float*)(wsb + 262144) + bc0);
        gv4 = f32x4{ g4.x, g4.y, g4.z, g4.w };
    } else {
        #pragma unroll
        for (int j = 0; j < 4; ++j) {
            const int col = bc0 + j;
            const float s0 = (col & 1) ? -C1f : C1f;
            const float s1 = ((col >> 1) & 1) ? -C2f : C2f;
            const float s2 = ((col >> 2) & 1) ? -C3f : C3f;
            gv4[j] = C3f * ba[col >> 3] + s2 * b2[col >> 3] + s1 * b1[col >> 2] + s0 * b0[col >> 1];
        }
    }

    // chunk = 16 rows x 512 f32 = 2048 float4; 4 per thread
    auto ldx = [&](int c, f32x4* v) {
        const f32x4* xb = (const f32x4*)(x + (rowblk + (long)c * CH) * 512);
        #pragma unroll
        for (int i = 0; i < 4; ++i) v[i] = xb[i * NT + tid];
    };
    auto stx = [&](int c, const f32x4* v) {
        char* base = lds + (c & 1) * CHSZ;
        #pragma unroll
        for (int i = 0; i < 4; ++i) {
            const int f = i * NT + tid;
            const int row = f >> 7, c4 = f & 127;
            u32x2 p = { pack2(v[i][0], v[i][1]), pack2(v[i][2], v[i][3]) };
            *(u32x2*)(base + row * RB + c4 * 8) = p;
        }
    };
    // compute one 16-row chunk: 16 ks MFMAs + 1 out f32x4 store
    auto compute = [&](int c) {
        const char* pa = lds + (c & 1) * CHSZ + (lane & 15) * RB + ((lane >> 4) * 16);
        f32x4 acc = {};
        #pragma unroll
        for (int ks = 0; ks < 16; ++ks) {
            bf16x8 a = cast8(*(const i32x4*)(pa + ks * 64));
            acc = __builtin_amdgcn_mfma_f32_16x16x32_bf16(B[ks], a, acc, 0, 0, 0);
        }
        const long r0 = rowblk + (long)c * CH + (lane & 15);
        *(f32x4*)(out + r0 * 512 + bc0) = acc + gv4;
    };

    // ---- prologue ----
    {
        f32x4 v[4];
        ldx(0, v);
        stx(0, v);                        // compiler waits vmcnt for v
    }
    lds_barrier();

    // ---- main loop: 1-deep pipeline, 2 resident blocks provide the overlap ----
    #pragma unroll 1
    for (int c = 0; c < NCHUNK; ++c) {
        f32x4 vn[4];
        if (c + 1 < NCHUNK) {
            ldx(c + 1, vn);               // issue early
            __builtin_amdgcn_sched_barrier(0);  // keep loads above compute
        }
        compute(c);
        if (c + 1 < NCHUNK) {
            vwait1();                     // waits the 4 x-loads; out-store stays in flight
            stx(c + 1, vn);
        }
        lds_barrier();
    }
}

extern "C" void kernel_launch(void* const* d_in, const int* in_sizes, int n_in,
                              void* d_out, int out_size, void* d_ws, size_t ws_size,
                              hipStream_t stream)
{
    const float* x  = (const float*)d_in[0];
    const float* W0 = (const float*)d_in[1];
    const float* b0 = (const float*)d_in[2];
    const float* W1 = (const float*)d_in[3];
    const float* b1 = (const float*)d_in[4];
    const float* W2 = (const float*)d_in[5];
    const float* b2 = (const float*)d_in[6];
    const float* Wa = (const float*)d_in[7];
    const float* ba = (const float*)d_in[8];
    float* out = (float*)d_out;

    const int nrows = in_sizes[0] / 512;          // 65536
    const int nblk  = (nrows / RPB) * NCOLG;      // 1024

    if (ws_size >= (size_t)(524288 + 2048)) {
        unsigned short* ws = (unsigned short*)d_ws;
        prep<<<128, 256, 0, stream>>>(W0, b0, W1, b1, W2, b2, Wa, ba, ws);
        wavelet_gemm<1><<<nblk, NT, 0, stream>>>(x, W0, b0, W1, b1, W2, b2, Wa, ba, ws, out, nblk);
    } else {
        wavelet_gemm<0><<<nblk, NT, 0, stream>>>(x, W0, b0, W1, b1, W2, b2, Wa, ba, nullptr, out, nblk);
    }
}